// Round 17
// baseline (75.784 us; speedup 1.0000x reference)
//
#include <hip/hip_runtime.h>

#define NGT 30000
#define NGTPAD 30016         // 1876 * 16
#define GTTILES 1876
#define PRSLOTS 3264         // m0 [0,160) m1 [160,784) m2 [784,3264), 16-pad
#define PRTILES 204
#define RB 128

typedef float v2f __attribute__((ext_vector_type(2)));
typedef __attribute__((ext_vector_type(8))) short bf16x8;
typedef __attribute__((ext_vector_type(4))) float f32x4;

// ws layout (float offsets); ws base 16B-aligned, all offsets 4-aligned.
#define OFF_PREDA   0               // 204*64*4  = 52224
#define OFF_PREDB   52224           // 52224
#define OFF_GTA     104448          // 1876*64*4 = 480256
#define OFF_GTB     584704          // 480256
#define OFF_G2      1064960         // 30016
#define OFF_P2      1094976         // 3264
#define OFF_GTMIN   1098240         // 3*30000 = 90000
#define OFF_PREDMIN 1188240         // 3264
#define OFF_PART    1191504         // RB*4 = 512
#define OFF_CTR     1192016         // 1 uint

__device__ __forceinline__ unsigned short f2bf(float f) {
    unsigned b = __float_as_uint(f);
    unsigned r = b + 0x7FFFu + ((b >> 16) & 1u);      // RNE
    return (unsigned short)(r >> 16);
}
__device__ __forceinline__ uint4 pack8(const unsigned short e[8]) {
    uint4 u;
    u.x = (unsigned)e[0] | ((unsigned)e[1] << 16);
    u.y = (unsigned)e[2] | ((unsigned)e[3] << 16);
    u.z = (unsigned)e[4] | ((unsigned)e[5] << 16);
    u.w = (unsigned)e[6] | ((unsigned)e[7] << 16);
    return u;
}

// ---------------------------------------------------------------------------
// Pack kernel (unchanged from R16, validated). Frag layout (m92/m97):
// lane&15 = row/col, lane>>4 = K-octet of 8 contiguous bf16; only octet 0
// nonzero (K=5 of 32). A rows: (-2x,-2y,-2z, n2hi, n2lo); pad rows carry
// 1e30 in slot 3. B cols: (x,y,z,1,1); pad cols zeros (guarded at atomic).
// ---------------------------------------------------------------------------
__global__ __launch_bounds__(256) void pack_kernel(
    const float* __restrict__ gt,
    const float* __restrict__ pbd0,
    const float* __restrict__ pbd1,
    const float* __restrict__ pbd2,
    uint4* __restrict__ predA, uint4* __restrict__ predB,
    uint4* __restrict__ gtA,   uint4* __restrict__ gtB,
    float* __restrict__ g2arr, float* __restrict__ p2arr,
    float* __restrict__ gtmin, float* __restrict__ predmin,
    unsigned* __restrict__ counter)
{
    const int i = blockIdx.x * 256 + threadIdx.x;
    if (i == 0) *counter = 0u;
    if (i < 90000) gtmin[i] = __int_as_float(0x7f7f7f7f);
    else if (i < 93264) predmin[i - 90000] = __int_as_float(0x7f7f7f7f);

    if (i < PRTILES * 64) {
        const int t = i >> 6, l = i & 63;
        unsigned short ea[8] = {0,0,0,0,0,0,0,0};
        unsigned short eb[8] = {0,0,0,0,0,0,0,0};
        if (l < 16) {
            const int slot = 16 * t + l;
            const int mesh = (slot < 160) ? 0 : (slot < 784) ? 1 : 2;
            const int j = slot - ((mesh == 0) ? 0 : (mesh == 1) ? 160 : 784);
            const int n = (mesh == 0) ? 156 : (mesh == 1) ? 618 : 2466;
            const float* pb = (mesh == 0) ? pbd0 : (mesh == 1) ? pbd1 : pbd2;
            if (j < n) {
                float x = pb[3*j], y = pb[3*j+1], z = pb[3*j+2];
                float p2 = x*x + y*y + z*z;
                unsigned short hi = f2bf(p2);
                float hif = __uint_as_float(((unsigned)hi) << 16);
                ea[0] = f2bf(-2.f*x); ea[1] = f2bf(-2.f*y); ea[2] = f2bf(-2.f*z);
                ea[3] = hi; ea[4] = f2bf(p2 - hif);
                eb[0] = f2bf(x); eb[1] = f2bf(y); eb[2] = f2bf(z);
                eb[3] = f2bf(1.f); eb[4] = f2bf(1.f);
                p2arr[slot] = p2;
            } else {
                ea[3] = f2bf(1.0e30f);      // pad row: never wins a min
                p2arr[slot] = 0.f;
            }
        }
        predA[i] = pack8(ea);
        predB[i] = pack8(eb);
    } else if (i < PRTILES * 64 + GTTILES * 64) {
        const int i2 = i - PRTILES * 64;
        const int u = i2 >> 6, l = i2 & 63;
        unsigned short ea[8] = {0,0,0,0,0,0,0,0};
        unsigned short eb[8] = {0,0,0,0,0,0,0,0};
        if (l < 16) {
            const int g = 16 * u + l;
            if (g < NGT) {
                float x = gt[3*g], y = gt[3*g+1], z = gt[3*g+2];
                float g2 = x*x + y*y + z*z;
                unsigned short hi = f2bf(g2);
                float hif = __uint_as_float(((unsigned)hi) << 16);
                ea[0] = f2bf(-2.f*x); ea[1] = f2bf(-2.f*y); ea[2] = f2bf(-2.f*z);
                ea[3] = hi; ea[4] = f2bf(g2 - hif);
                eb[0] = f2bf(x); eb[1] = f2bf(y); eb[2] = f2bf(z);
                eb[3] = f2bf(1.f); eb[4] = f2bf(1.f);
                g2arr[g] = g2;
            } else {
                ea[3] = f2bf(1.0e30f);
                g2arr[g] = 0.f;
            }
        }
        gtA[i2] = pack8(ea);
        gtB[i2] = pack8(eb);
    }
}

// ---------------------------------------------------------------------------
// MFMA chamfer with 4x B-fragment reuse (R17). grid = 469 + 204 = 673
// blocks x 256 (4 waves). R16 post-mortem: reuse=1 streamed ~766 MB of
// A-frags through L2 (~22us floor) with a serial load->MFMA chain. Now each
// wave holds FOUR B-frags and issues 4 independent MFMAs per A-frag load.
// gt-side (bid<469): wave = (gt tile group of 4) x (pred quarter of 51);
//   per mesh-segment intersection: scan pred A-frags, 4 MFMAs each,
//   rmin[b] accumulate; epilogue shfl 16/32 -> atomicMin gtmin[m][g] (+g2).
// pred-side (bid>=469): wave = (pred tile group of 4) x (gt 1/16 chunk of
//   ~118); scan gt A-frags; epilogue -> atomicMin predmin[slot] (+p2,
//   validity-guarded).
// atomicMin on int bits: values >= -0.05 (bf16 slop) -- bounded error,
// order-independent, deterministic; init 0x7f7f7f7f.
// ---------------------------------------------------------------------------
__global__ __launch_bounds__(256) void chamfer_kernel(
    const uint4* __restrict__ predA, const uint4* __restrict__ predB,
    const uint4* __restrict__ gtA,   const uint4* __restrict__ gtB,
    const float* __restrict__ g2arr, const float* __restrict__ p2arr,
    float* __restrict__ gtmin, float* __restrict__ predmin)
{
    const int tid = threadIdx.x;
    const int lane = tid & 63, wid = tid >> 6;
    const int bid = blockIdx.x;
    const f32x4 zero = {0.f, 0.f, 0.f, 0.f};
    union { uint4 u; bf16x8 b; } cv;

    if (bid < 469) {
        const int unit = bid * 4 + wid;          // 0..1875
        const int u4 = unit >> 2, q = unit & 3;  // gt group, pred quarter
        bf16x8 bfrag[4];
        #pragma unroll
        for (int b = 0; b < 4; ++b) {
            cv.u = gtB[(u4 * 4 + b) * 64 + lane];
            bfrag[b] = cv.b;
        }
        const int qlo = q * 51, qhi = qlo + 51;
        const int seglo[3] = {0, 10, 49}, seghi[3] = {10, 49, 204};
        #pragma unroll
        for (int m = 0; m < 3; ++m) {
            const int lo = max(seglo[m], qlo), hi = min(seghi[m], qhi);
            if (lo >= hi) continue;
            float rmin[4] = {3.0e38f, 3.0e38f, 3.0e38f, 3.0e38f};
            #pragma unroll 2
            for (int t = lo; t < hi; ++t) {
                cv.u = predA[t * 64 + lane];
                const bf16x8 afrag = cv.b;
                #pragma unroll
                for (int b = 0; b < 4; ++b) {
                    f32x4 acc = __builtin_amdgcn_mfma_f32_16x16x32_bf16(
                        afrag, bfrag[b], zero, 0, 0, 0);
                    rmin[b] = fminf(rmin[b], fminf(fminf(acc.x, acc.y),
                                                   fminf(acc.z, acc.w)));
                }
            }
            #pragma unroll
            for (int b = 0; b < 4; ++b) {
                float v = rmin[b];
                v = fminf(v, __shfl_xor(v, 16, 64));
                v = fminf(v, __shfl_xor(v, 32, 64));
                if (lane < 16) {
                    const int g = (u4 * 4 + b) * 16 + lane;
                    if (g < NGT)
                        atomicMin((int*)(gtmin + m * NGT + g),
                                  __float_as_int(v + g2arr[g]));
                }
            }
        }
    } else {
        const int unit = (bid - 469) * 4 + wid;   // 0..815
        const int pg = unit >> 4, cc = unit & 15; // pred group, gt chunk
        bf16x8 bfrag[4];
        #pragma unroll
        for (int b = 0; b < 4; ++b) {
            cv.u = predB[(pg * 4 + b) * 64 + lane];
            bfrag[b] = cv.b;
        }
        const int lo = cc * 118, hi = min(GTTILES, lo + 118);
        float rmin[4] = {3.0e38f, 3.0e38f, 3.0e38f, 3.0e38f};
        #pragma unroll 2
        for (int t = lo; t < hi; ++t) {
            cv.u = gtA[t * 64 + lane];
            const bf16x8 afrag = cv.b;
            #pragma unroll
            for (int b = 0; b < 4; ++b) {
                f32x4 acc = __builtin_amdgcn_mfma_f32_16x16x32_bf16(
                    afrag, bfrag[b], zero, 0, 0, 0);
                rmin[b] = fminf(rmin[b], fminf(fminf(acc.x, acc.y),
                                               fminf(acc.z, acc.w)));
            }
        }
        #pragma unroll
        for (int b = 0; b < 4; ++b) {
            float v = rmin[b];
            v = fminf(v, __shfl_xor(v, 16, 64));
            v = fminf(v, __shfl_xor(v, 32, 64));
            if (lane < 16) {
                const int s = (pg * 4 + b) * 16 + lane;
                const bool valid = (s < 156) || (s >= 160 && s < 778) ||
                                   (s >= 784 && s < 3250);
                if (valid)
                    atomicMin((int*)(predmin + s),
                              __float_as_int(v + p2arr[s]));
            }
        }
    }
}

// ---------------------------------------------------------------------------
// Partial reduce + fused final (last-block pattern), unchanged from R16.
// ---------------------------------------------------------------------------
__global__ __launch_bounds__(256) void partial_kernel(
    const float* __restrict__ pc0, const float* __restrict__ pc1, const float* __restrict__ pc2,
    const float* __restrict__ pbd0, const float* __restrict__ pbd1, const float* __restrict__ pbd2,
    const int* __restrict__ ed0, const int* __restrict__ ed1, const int* __restrict__ ed2,
    const int* __restrict__ li0, const int* __restrict__ li1, const int* __restrict__ li2,
    const float* __restrict__ gtmin, const float* __restrict__ predmin,
    float* __restrict__ partials, unsigned* __restrict__ counter,
    float* __restrict__ out)
{
    const int   NEs[3]   = {462, 1848, 7392};
    const int   eoffs[3] = {0, 462, 2310};
    const float lapc[3]  = {0.2f, 1.0f, 1.0f};
    const int   NVs[3]   = {156, 618, 2466};
    const int   poffs[3] = {0, 156, 774};
    const float* pcs[3]  = {pc0, pc1, pc2};
    const float* pbds[3] = {pbd0, pbd1, pbd2};
    const int*   eds[3]  = {ed0, ed1, ed2};
    const int*   lis[3]  = {li0, li1, li2};

    const int tid = threadIdx.x;
    const int stride = gridDim.x * 256;
    float ch = 0.f, ed = 0.f, lp = 0.f;

    for (int idx = blockIdx.x * 256 + tid; idx < 38706; idx += stride) {
        if (idx < 22500) {
            const float4 q = ((const float4*)gtmin)[idx];
            ch += (q.x + q.y + q.z + q.w) * (1.0f / 30000.0f);
        } else if (idx < 25764) {
            const int s = idx - 22500;
            if (s < 156)                    ch += predmin[s] * (1.0f / 156.0f);
            else if (s >= 160 && s < 778)   ch += predmin[s] * (1.0f / 618.0f);
            else if (s >= 784 && s < 3250)  ch += predmin[s] * (1.0f / 2466.0f);
        } else if (idx < 35466) {
            int e = idx - 25764;
            int m = (e < 462) ? 0 : (e < 2310) ? 1 : 2;
            int el = e - eoffs[m];
            const int* E = eds[m];
            const float* P = pcs[m];
            int a = E[2*el], b = E[2*el+1];
            float dx = P[3*a]   - P[3*b];
            float dy = P[3*a+1] - P[3*b+1];
            float dz = P[3*a+2] - P[3*b+2];
            ed += (dx*dx + dy*dy + dz*dz) * (300.0f / (float)NEs[m]);
        } else {
            int v = idx - 35466;
            int m = (v < 156) ? 0 : (v < 774) ? 1 : 2;
            int vl = v - poffs[m];
            const int* L = lis[m];
            const float* PB = pbds[m];
            const float* PC = pcs[m];
            float mvx = PB[3*vl]   - PC[3*vl];
            float mvy = PB[3*vl+1] - PC[3*vl+1];
            float mvz = PB[3*vl+2] - PC[3*vl+2];
            float sx = 0.f, sy = 0.f, sz = 0.f;
            #pragma unroll
            for (int k = 0; k < 8; ++k) {
                int nb = L[10*vl + k];
                if (nb >= 0) {
                    sx += PB[3*nb]   - PC[3*nb];
                    sy += PB[3*nb+1] - PC[3*nb+1];
                    sz += PB[3*nb+2] - PC[3*nb+2];
                }
            }
            float invdeg = 1.0f / (float)L[10*vl + 9];
            float dx = mvx - sx * invdeg;
            float dy = mvy - sy * invdeg;
            float dz = mvz - sz * invdeg;
            float t = dx*dx + dy*dy + dz*dz;
            if (m > 0) t += mvx*mvx + mvy*mvy + mvz*mvz;
            lp += t * (lapc[m] / (float)NVs[m]);
        }
    }

    __shared__ float sred[12];
    __shared__ int is_last;
    for (int off = 32; off; off >>= 1) {
        ch += __shfl_down(ch, off, 64);
        ed += __shfl_down(ed, off, 64);
        lp += __shfl_down(lp, off, 64);
    }
    const int lane = tid & 63, wid = tid >> 6;
    if (lane == 0) { sred[wid] = ch; sred[4 + wid] = ed; sred[8 + wid] = lp; }
    __syncthreads();
    if (tid == 0) {
        partials[blockIdx.x * 4 + 0] = sred[0] + sred[1] + sred[2] + sred[3];
        partials[blockIdx.x * 4 + 1] = sred[4] + sred[5] + sred[6] + sred[7];
        partials[blockIdx.x * 4 + 2] = sred[8] + sred[9] + sred[10] + sred[11];
        __threadfence();
        unsigned prev = atomicAdd(counter, 1u);
        is_last = (prev == (unsigned)(gridDim.x - 1)) ? 1 : 0;
    }
    __syncthreads();

    if (is_last) {
        __threadfence();
        float c2 = 0.f, e2 = 0.f, l2 = 0.f;
        if (tid < RB) {
            c2 = partials[4*tid]; e2 = partials[4*tid+1]; l2 = partials[4*tid+2];
        }
        for (int off = 32; off; off >>= 1) {
            c2 += __shfl_down(c2, off, 64);
            e2 += __shfl_down(e2, off, 64);
            l2 += __shfl_down(l2, off, 64);
        }
        __shared__ float s2[12];
        if (lane == 0) { s2[wid] = c2; s2[4 + wid] = e2; s2[8 + wid] = l2; }
        __syncthreads();
        if (tid == 0) {
            float C = s2[0] + s2[1];
            float E = s2[4] + s2[5];
            float L = s2[8] + s2[9];
            out[0] = 100.0f * C + 0.1f * E + 0.3f * L;
            out[1] = C;
            out[2] = E;
            out[3] = L;
        }
    }
}

extern "C" void kernel_launch(void* const* d_in, const int* in_sizes, int n_in,
                              void* d_out, int out_size, void* d_ws, size_t ws_size,
                              hipStream_t stream) {
    const float* gt   = (const float*)d_in[0];
    const float* pc0  = (const float*)d_in[1];
    const float* pbd0 = (const float*)d_in[2];
    const int*   ed0  = (const int*)  d_in[3];
    const int*   li0  = (const int*)  d_in[4];
    const float* pc1  = (const float*)d_in[5];
    const float* pbd1 = (const float*)d_in[6];
    const int*   ed1  = (const int*)  d_in[7];
    const int*   li1  = (const int*)  d_in[8];
    const float* pc2  = (const float*)d_in[9];
    const float* pbd2 = (const float*)d_in[10];
    const int*   ed2  = (const int*)  d_in[11];
    const int*   li2  = (const int*)  d_in[12];

    float* ws         = (float*)d_ws;
    uint4* predA      = (uint4*)(ws + OFF_PREDA);
    uint4* predB      = (uint4*)(ws + OFF_PREDB);
    uint4* gtA        = (uint4*)(ws + OFF_GTA);
    uint4* gtB        = (uint4*)(ws + OFF_GTB);
    float* g2arr      = ws + OFF_G2;
    float* p2arr      = ws + OFF_P2;
    float* gtmin      = ws + OFF_GTMIN;
    float* predmin    = ws + OFF_PREDMIN;
    float* partials   = ws + OFF_PART;
    unsigned* counter = (unsigned*)(ws + OFF_CTR);
    float* out        = (float*)d_out;

    const int packN = (PRTILES + GTTILES) * 64;   // 133120
    pack_kernel<<<(packN + 255) / 256, 256, 0, stream>>>(
        gt, pbd0, pbd1, pbd2, predA, predB, gtA, gtB,
        g2arr, p2arr, gtmin, predmin, counter);

    chamfer_kernel<<<469 + 204, 256, 0, stream>>>(
        predA, predB, gtA, gtB, g2arr, p2arr, gtmin, predmin);

    partial_kernel<<<RB, 256, 0, stream>>>(pc0, pc1, pc2, pbd0, pbd1, pbd2,
                                           ed0, ed1, ed2, li0, li1, li2,
                                           gtmin, predmin, partials, counter, out);
}

// Round 18
// 44.218 us; speedup vs baseline: 1.7139x; 1.7139x over previous
//
#include <hip/hip_runtime.h>

#define NGT 30000
#define GT_TILE 512
#define NBLK_G 59            // ceil(30000/512)
#define PRANGE 128           // preds per block
#define NCHUNK 27            // m0: 2, m1: 5, m2: 20 chunks of 128
#define NPACK 3456           // 27 * 128 chunk-padded pred slots
#define RB 128               // reduce blocks

typedef float v2f __attribute__((ext_vector_type(2)));

// ws layout (float offsets). predpack first (16B aligned at ws base).
#define OFF_PREDPACK 0              // 3456 float4 = 13824 floats
#define OFF_GTMIN    13824          // 3*30000 = 90000 (16B-aligned)
#define OFF_PREDMIN  103824         // 3240
#define OFF_PARTIALS 107064         // RB*4 = 512
#define OFF_COUNTER  107576         // 1 uint

// ---------------------------------------------------------------------------
// Pack kernel: predpack[i] = {x,y,z,norm} (sentinel w=3e38 for pad slots);
// inits gtmin[90000] + predmin[3240] to huge and zeroes the done-counter
// (replaces the memset dispatch). predpack: m0 [0,256), m1 [256,896),
// m2 [896,3456). Grid covers 93240 init slots.
// ---------------------------------------------------------------------------
__global__ __launch_bounds__(256) void pack_kernel(
    const float* __restrict__ pbd0,
    const float* __restrict__ pbd1,
    const float* __restrict__ pbd2,
    float4* __restrict__ predpack,
    float* __restrict__ gtmin,
    float* __restrict__ predmin,
    unsigned* __restrict__ counter)
{
    const int i = blockIdx.x * 256 + threadIdx.x;
    if (i == 0) *counter = 0u;
    if (i < 90000) gtmin[i] = __int_as_float(0x7f7f7f7f);
    else if (i < 93240) predmin[i - 90000] = __int_as_float(0x7f7f7f7f);
    if (i >= NPACK) return;
    int mesh, j, n;
    if (i < 256)      { mesh = 0; j = i;       n = 156; }
    else if (i < 896) { mesh = 1; j = i - 256; n = 618; }
    else              { mesh = 2; j = i - 896; n = 2466; }
    const float* p = (mesh == 0) ? pbd0 : (mesh == 1) ? pbd1 : pbd2;
    float4 v = make_float4(0.f, 0.f, 0.f, 3.0e38f);
    if (j < n) {
        float x = p[3*j], y = p[3*j+1], z = p[3*j+2];
        v = make_float4(x, y, z, x*x + y*y + z*z);
    }
    predpack[i] = v;
}

// ---------------------------------------------------------------------------
// Two-phase chamfer (R11 structure — best measured 44.9us total — with the
// gtpart indirection removed: phase 1 atomicMins straight into gtmin).
// grid = (59, 27) = 1593 blocks, block = 256. LDS: sgt[512]+spred[128] 10KB.
// Phase 1: 2 gt/thread as v2f; 128 preds via wave-uniform s_load_dwordx4
//          from predpack (2 KB slice, K$-shared by same-y blocks); packed
//          v_pk_fma (~3 VALU/pair); atomicMin gtmin[m][g] (27 chunk-blocks
//          combine; int bits of non-negative floats: exact,
//          order-independent, deterministic; init 0x7f7f7f7f).
// Phase 2: 8-lane groups own 4 preds (component-packed v2f); lane s scans
//          interleaved slice sgt[k*8+s] (8 distinct 16B addrs/wave ->
//          32 banks, conflict-free); 3-level shfl_xor -> atomicMin predmin.
// Sentinel slots carry w=3e38 so they never win a min.
// MFMA path (R16/R17) abandoned: allocator cliffs (VGPR 256) + L2 fragment
// stream made it strictly worse than this VALU/LDS form.
// ---------------------------------------------------------------------------
__global__ __launch_bounds__(256) void chamfer_kernel(
    const float* __restrict__ gt,
    const float4* __restrict__ predpack,
    float* __restrict__ gtmin,     // [3*NGT], pre-init by pack_kernel
    float* __restrict__ predmin)   // [3240],  pre-init by pack_kernel
{
    __shared__ float4 sgt[GT_TILE];
    __shared__ float4 spred[PRANGE];

    const int tid = threadIdx.x;
    const int c = blockIdx.y;

    int mesh, cidx;
    if (c < 2)      { mesh = 0; cidx = c; }
    else if (c < 7) { mesh = 1; cidx = c - 2; }
    else            { mesh = 2; cidx = c - 7; }
    const int coff = cidx * PRANGE;
    const int n    = (mesh == 0) ? 156 : (mesh == 1) ? 618 : 2466;
    const int poff = (mesh == 0) ? 0   : (mesh == 1) ? 156 : 774;
    const int pbase = ((mesh == 0) ? 0 : (mesh == 1) ? 256 : 896) + coff;
    const int np = min(PRANGE, n - coff);

    if (tid < PRANGE) spred[tid] = predpack[pbase + tid];

    const int gbase = blockIdx.x * GT_TILE;
    float gx[2], gy[2], gz[2], g2[2];
    #pragma unroll
    for (int k = 0; k < 2; ++k) {
        const int g = gbase + k * 256 + tid;
        float x = 1e18f, y = 1e18f, z = 1e18f;   // sentinel gt: huge, finite
        if (g < NGT) { x = gt[3*g]; y = gt[3*g+1]; z = gt[3*g+2]; }
        gx[k] = x; gy[k] = y; gz[k] = z;
        g2[k] = x*x + y*y + z*z;
        sgt[k * 256 + tid] = make_float4(x, y, z, g2[k]);
    }
    __syncthreads();

    // ---- phase 1: gt-side min; uniform s_load preds + packed f32 math ----
    {
        v2f gxv = {gx[0], gx[1]};
        v2f gyv = {gy[0], gy[1]};
        v2f gzv = {gz[0], gz[1]};
        v2f gminv = {3.0e38f, 3.0e38f};
        const float4* __restrict__ pp = predpack + pbase;  // uniform base
        #pragma unroll 8
        for (int j = 0; j < PRANGE; ++j) {
            const float4 p = pp[j];              // uniform -> s_load_dwordx4
            v2f dot = gxv * p.x;
            dot += gyv * p.y;                    // v_pk_fma
            dot += gzv * p.z;
            v2f t = dot * -2.0f + p.w;           // p2 - 2*dot (packed fma)
            gminv.x = fminf(gminv.x, t.x);
            gminv.y = fminf(gminv.y, t.y);
        }
        int g = gbase + tid;
        if (g < NGT)
            atomicMin((int*)(gtmin + mesh * NGT + g),
                      __float_as_int(gminv.x + g2[0]));
        g += 256;
        if (g < NGT)
            atomicMin((int*)(gtmin + mesh * NGT + g),
                      __float_as_int(gminv.y + g2[1]));
    }

    // ---- phase 2: 8-lane groups x 4 preds component-packed, packed f32 ----
    {
        const int grp = tid >> 3;                  // 0..31 -> preds 4g..4g+3
        const int s   = tid & 7;                   // interleaved slice
        const float4 P0 = spred[4*grp+0], P1 = spred[4*grp+1];
        const float4 P2 = spred[4*grp+2], P3 = spred[4*grp+3];
        v2f px01 = {P0.x, P1.x}, px23 = {P2.x, P3.x};
        v2f py01 = {P0.y, P1.y}, py23 = {P2.y, P3.y};
        v2f pz01 = {P0.z, P1.z}, pz23 = {P2.z, P3.z};
        v2f mn01 = {3.0e38f, 3.0e38f}, mn23 = {3.0e38f, 3.0e38f};
        #pragma unroll 4
        for (int k = 0; k < GT_TILE / 8; ++k) {
            const float4 q = sgt[k * 8 + s];       // 8 addrs -> banks 0..31
            v2f d01 = px01 * q.x; d01 += py01 * q.y; d01 += pz01 * q.z;
            v2f d23 = px23 * q.x; d23 += py23 * q.y; d23 += pz23 * q.z;
            v2f t01 = d01 * -2.0f + q.w;           // g2 - 2*dot
            v2f t23 = d23 * -2.0f + q.w;
            mn01.x = fminf(mn01.x, t01.x); mn01.y = fminf(mn01.y, t01.y);
            mn23.x = fminf(mn23.x, t23.x); mn23.y = fminf(mn23.y, t23.y);
        }
        float mn[4] = {mn01.x, mn01.y, mn23.x, mn23.y};
        float pw[4] = {P0.w, P1.w, P2.w, P3.w};
        #pragma unroll
        for (int off = 1; off < 8; off <<= 1) {
            #pragma unroll
            for (int r = 0; r < 4; ++r)
                mn[r] = fminf(mn[r], __shfl_xor(mn[r], off, 64));
        }
        if (s == 0) {
            #pragma unroll
            for (int r = 0; r < 4; ++r) {
                const int pj = 4*grp + r;
                if (pj < np)
                    atomicMin((int*)(predmin + poff + coff + pj),
                              __float_as_int(mn[r] + pw[r]));
            }
        }
    }
}

// ---------------------------------------------------------------------------
// Partial reduce + fused final (last-block pattern).
// Index space: [0,22500) gtmin float4 (all x 1/30000) | [22500,25740)
// predmin | [25740,35442) edges | [35442,38682) laplace.
// Last block sums the 128 partials in fixed tree order -> deterministic.
// ---------------------------------------------------------------------------
__global__ __launch_bounds__(256) void partial_kernel(
    const float* __restrict__ pc0, const float* __restrict__ pc1, const float* __restrict__ pc2,
    const float* __restrict__ pbd0, const float* __restrict__ pbd1, const float* __restrict__ pbd2,
    const int* __restrict__ ed0, const int* __restrict__ ed1, const int* __restrict__ ed2,
    const int* __restrict__ li0, const int* __restrict__ li1, const int* __restrict__ li2,
    const float* __restrict__ gtmin, const float* __restrict__ predmin,
    float* __restrict__ partials, unsigned* __restrict__ counter,
    float* __restrict__ out)
{
    const int   NVs[3]   = {156, 618, 2466};
    const int   NEs[3]   = {462, 1848, 7392};
    const int   poffs[3] = {0, 156, 774};
    const int   eoffs[3] = {0, 462, 2310};
    const float lapc[3]  = {0.2f, 1.0f, 1.0f};
    const float* pcs[3]  = {pc0, pc1, pc2};
    const float* pbds[3] = {pbd0, pbd1, pbd2};
    const int*   eds[3]  = {ed0, ed1, ed2};
    const int*   lis[3]  = {li0, li1, li2};

    const int tid = threadIdx.x;
    const int stride = gridDim.x * 256;
    float ch = 0.f, ed = 0.f, lp = 0.f;

    for (int idx = blockIdx.x * 256 + tid; idx < 38682; idx += stride) {
        if (idx < 22500) {
            const float4 q = ((const float4*)gtmin)[idx];
            ch += (q.x + q.y + q.z + q.w) * (1.0f / 30000.0f);
        } else if (idx < 25740) {
            int p = idx - 22500;
            int m = (p < 156) ? 0 : (p < 774) ? 1 : 2;
            ch += predmin[p] * (1.0f / (float)NVs[m]);
        } else if (idx < 35442) {
            int e = idx - 25740;
            int m = (e < 462) ? 0 : (e < 2310) ? 1 : 2;
            int el = e - eoffs[m];
            const int* E = eds[m];
            const float* P = pcs[m];
            int a = E[2*el], b = E[2*el+1];
            float dx = P[3*a]   - P[3*b];
            float dy = P[3*a+1] - P[3*b+1];
            float dz = P[3*a+2] - P[3*b+2];
            ed += (dx*dx + dy*dy + dz*dz) * (300.0f / (float)NEs[m]);
        } else {
            int v = idx - 35442;
            int m = (v < 156) ? 0 : (v < 774) ? 1 : 2;
            int vl = v - poffs[m];
            const int* L = lis[m];
            const float* PB = pbds[m];
            const float* PC = pcs[m];
            float mvx = PB[3*vl]   - PC[3*vl];
            float mvy = PB[3*vl+1] - PC[3*vl+1];
            float mvz = PB[3*vl+2] - PC[3*vl+2];
            float sx = 0.f, sy = 0.f, sz = 0.f;
            #pragma unroll
            for (int k = 0; k < 8; ++k) {
                int nb = L[10*vl + k];
                if (nb >= 0) {
                    sx += PB[3*nb]   - PC[3*nb];
                    sy += PB[3*nb+1] - PC[3*nb+1];
                    sz += PB[3*nb+2] - PC[3*nb+2];
                }
            }
            float invdeg = 1.0f / (float)L[10*vl + 9];
            float dx = mvx - sx * invdeg;
            float dy = mvy - sy * invdeg;
            float dz = mvz - sz * invdeg;
            float t = dx*dx + dy*dy + dz*dz;
            if (m > 0) t += mvx*mvx + mvy*mvy + mvz*mvz;
            lp += t * (lapc[m] / (float)NVs[m]);
        }
    }

    __shared__ float sred[12];
    __shared__ int is_last;
    for (int off = 32; off; off >>= 1) {
        ch += __shfl_down(ch, off, 64);
        ed += __shfl_down(ed, off, 64);
        lp += __shfl_down(lp, off, 64);
    }
    const int lane = tid & 63, wid = tid >> 6;
    if (lane == 0) { sred[wid] = ch; sred[4 + wid] = ed; sred[8 + wid] = lp; }
    __syncthreads();
    if (tid == 0) {
        partials[blockIdx.x * 4 + 0] = sred[0] + sred[1] + sred[2] + sred[3];
        partials[blockIdx.x * 4 + 1] = sred[4] + sred[5] + sred[6] + sred[7];
        partials[blockIdx.x * 4 + 2] = sred[8] + sred[9] + sred[10] + sred[11];
        __threadfence();
        unsigned prev = atomicAdd(counter, 1u);
        is_last = (prev == (unsigned)(gridDim.x - 1)) ? 1 : 0;
    }
    __syncthreads();

    if (is_last) {
        __threadfence();
        float c2 = 0.f, e2 = 0.f, l2 = 0.f;
        if (tid < RB) {
            c2 = partials[4*tid]; e2 = partials[4*tid+1]; l2 = partials[4*tid+2];
        }
        for (int off = 32; off; off >>= 1) {
            c2 += __shfl_down(c2, off, 64);
            e2 += __shfl_down(e2, off, 64);
            l2 += __shfl_down(l2, off, 64);
        }
        __shared__ float s2[12];
        if (lane == 0) { s2[wid] = c2; s2[4 + wid] = e2; s2[8 + wid] = l2; }
        __syncthreads();
        if (tid == 0) {
            float C = s2[0] + s2[1];       // wids 2,3 contributed zeros
            float E = s2[4] + s2[5];
            float L = s2[8] + s2[9];
            out[0] = 100.0f * C + 0.1f * E + 0.3f * L;
            out[1] = C;
            out[2] = E;
            out[3] = L;
        }
    }
}

extern "C" void kernel_launch(void* const* d_in, const int* in_sizes, int n_in,
                              void* d_out, int out_size, void* d_ws, size_t ws_size,
                              hipStream_t stream) {
    const float* gt   = (const float*)d_in[0];
    const float* pc0  = (const float*)d_in[1];
    const float* pbd0 = (const float*)d_in[2];
    const int*   ed0  = (const int*)  d_in[3];
    const int*   li0  = (const int*)  d_in[4];
    const float* pc1  = (const float*)d_in[5];
    const float* pbd1 = (const float*)d_in[6];
    const int*   ed1  = (const int*)  d_in[7];
    const int*   li1  = (const int*)  d_in[8];
    const float* pc2  = (const float*)d_in[9];
    const float* pbd2 = (const float*)d_in[10];
    const int*   ed2  = (const int*)  d_in[11];
    const int*   li2  = (const int*)  d_in[12];

    float* ws         = (float*)d_ws;
    float4* predpack  = (float4*)(ws + OFF_PREDPACK);
    float* gtmin      = ws + OFF_GTMIN;
    float* predmin    = ws + OFF_PREDMIN;
    float* partials   = ws + OFF_PARTIALS;
    unsigned* counter = (unsigned*)(ws + OFF_COUNTER);
    float* out        = (float*)d_out;

    pack_kernel<<<(93240 + 255) / 256, 256, 0, stream>>>(
        pbd0, pbd1, pbd2, predpack, gtmin, predmin, counter);

    dim3 grid(NBLK_G, NCHUNK);
    chamfer_kernel<<<grid, 256, 0, stream>>>(gt, predpack, gtmin, predmin);

    partial_kernel<<<RB, 256, 0, stream>>>(pc0, pc1, pc2, pbd0, pbd1, pbd2,
                                           ed0, ed1, ed2, li0, li1, li2,
                                           gtmin, predmin, partials, counter, out);
}